// Round 2
// baseline (1064.088 us; speedup 1.0000x reference)
//
#include <hip/hip_runtime.h>
#include <hip/hip_bf16.h>

#define NN   50000
#define NE   600000
#define INF  602
#define HID  128
#define OUTF 41

// ---------------- degree histogram ----------------
__global__ __launch_bounds__(256) void deg_hist_k(const int* __restrict__ src,
                                                  const int* __restrict__ dst,
                                                  int* __restrict__ cnt_out,
                                                  int* __restrict__ cnt_in, int E) {
    int e = blockIdx.x * 256 + threadIdx.x;
    if (e < E) {
        atomicAdd(&cnt_out[src[e]], 1);
        atomicAdd(&cnt_in[dst[e]], 1);
    }
}

// ---------------- single-block exclusive scan (chunked) ----------------
__global__ __launch_bounds__(1024) void scan_k(const int* __restrict__ cnt,
                                               int* __restrict__ rowptr,
                                               int* __restrict__ wcur, int n) {
    __shared__ int tmp[1024];
    int tid = threadIdx.x;
    int chunk = (n + 1023) >> 10;
    int beg = tid * chunk;
    int end = beg + chunk;
    if (beg > n) beg = n;
    if (end > n) end = n;
    int s = 0;
    for (int i = beg; i < end; ++i) s += cnt[i];
    tmp[tid] = s;
    __syncthreads();
    for (int off = 1; off < 1024; off <<= 1) {
        int t = (tid >= off) ? tmp[tid - off] : 0;
        __syncthreads();
        tmp[tid] += t;
        __syncthreads();
    }
    if (tid == 1023) rowptr[n] = tmp[1023];
    int run = tmp[tid] - s;  // exclusive prefix of this chunk
    for (int i = beg; i < end; ++i) {
        rowptr[i] = run;
        wcur[i] = run;
        run += cnt[i];
    }
}

// ---------------- CSR fill ----------------
__global__ __launch_bounds__(256) void fill_csr_k(const int* __restrict__ src,
                                                  const int* __restrict__ dst,
                                                  int* __restrict__ wcur,
                                                  int* __restrict__ csrsrc, int E) {
    int e = blockIdx.x * 256 + threadIdx.x;
    if (e < E) {
        int p = atomicAdd(&wcur[dst[e]], 1);
        csrsrc[p] = src[e];
    }
}

// ---------------- rsqrt of clipped degrees ----------------
__global__ __launch_bounds__(256) void make_rs_k(const int* __restrict__ cnt_out,
                                                 const int* __restrict__ cnt_in,
                                                 float* __restrict__ rs_out,
                                                 float* __restrict__ rs_in, int n) {
    int i = blockIdx.x * 256 + threadIdx.x;
    if (i < n) {
        int co = cnt_out[i]; if (co < 1) co = 1;
        int ci = cnt_in[i];  if (ci < 1) ci = 1;
        rs_out[i] = rsqrtf((float)co);
        rs_in[i]  = rsqrtf((float)ci);
    }
}

// ---------------- tiled GEMM: C[n,128] = (scale? rs[i]*A[i,:] : A[i,:]) @ W[K,128] ----------------
template <bool SCALE>
__global__ __launch_bounds__(256) void gemm_k(const float* __restrict__ A, int K,
                                              const float* __restrict__ W,
                                              const float* __restrict__ rs,
                                              float* __restrict__ C, int n) {
    __shared__ float As[32][17];   // +1 pad
    __shared__ float Ws[16][128];
    int tid = threadIdx.x;
    int rowBase = blockIdx.x * 32;
    int trow = tid >> 5;   // 0..7  -> 4 rows each
    int tcol = tid & 31;   // 0..31 -> 4 cols each
    float acc[4][4] = {{0.f}};

    for (int kb = 0; kb < K; kb += 16) {
        // A tile: 32 rows x 16 k
        for (int i = tid; i < 512; i += 256) {
            int r = i >> 4, kk = i & 15;
            int grow = rowBase + r, gk = kb + kk;
            float v = 0.f;
            if (grow < n && gk < K) {
                v = A[(size_t)grow * K + gk];
                if (SCALE) v *= rs[grow];
            }
            As[r][kk] = v;
        }
        // W tile: 16 k x 128 cols
        for (int i = tid; i < 2048; i += 256) {
            int kk = i >> 7, c = i & 127;
            int gk = kb + kk;
            Ws[kk][c] = (gk < K) ? W[(size_t)gk * HID + c] : 0.f;
        }
        __syncthreads();
#pragma unroll
        for (int kk = 0; kk < 16; ++kk) {
            float4 wv = *(const float4*)(&Ws[kk][tcol * 4]);
            float a0 = As[trow * 4 + 0][kk];
            float a1 = As[trow * 4 + 1][kk];
            float a2 = As[trow * 4 + 2][kk];
            float a3 = As[trow * 4 + 3][kk];
            acc[0][0] += a0 * wv.x; acc[0][1] += a0 * wv.y; acc[0][2] += a0 * wv.z; acc[0][3] += a0 * wv.w;
            acc[1][0] += a1 * wv.x; acc[1][1] += a1 * wv.y; acc[1][2] += a1 * wv.z; acc[1][3] += a1 * wv.w;
            acc[2][0] += a2 * wv.x; acc[2][1] += a2 * wv.y; acc[2][2] += a2 * wv.z; acc[2][3] += a2 * wv.w;
            acc[3][0] += a3 * wv.x; acc[3][1] += a3 * wv.y; acc[3][2] += a3 * wv.z; acc[3][3] += a3 * wv.w;
        }
        __syncthreads();
    }
    for (int r = 0; r < 4; ++r) {
        int grow = rowBase + trow * 4 + r;
        if (grow < n) {
            float4 v = {acc[r][0], acc[r][1], acc[r][2], acc[r][3]};
            *(float4*)&C[(size_t)grow * HID + tcol * 4] = v;
        }
    }
}

// ---------------- gather + finish: one wave per node, lane = 2 features ----------------
__global__ __launch_bounds__(256) void gather_k(const float* __restrict__ H,
                                                const int* __restrict__ rowptr,
                                                const int* __restrict__ csrsrc,
                                                const float* __restrict__ rs_in,
                                                const float* __restrict__ rs_out,
                                                const float* __restrict__ bias,
                                                const float* __restrict__ resid,  // nullable
                                                float* __restrict__ outX,         // nullable
                                                float* __restrict__ outXs,        // nullable
                                                int n) {
    int node = blockIdx.x * 4 + (threadIdx.x >> 6);
    if (node >= n) return;
    int lane = threadIdx.x & 63;
    int beg = rowptr[node], end = rowptr[node + 1];
    float ax = 0.f, ay = 0.f;
    for (int p = beg; p < end; ++p) {
        int s = csrsrc[p];
        float2 h = *(const float2*)(H + (size_t)s * HID + lane * 2);
        ax += h.x;
        ay += h.y;
    }
    float ri = rs_in[node];
    float bx = bias[lane * 2];
    float by = bias[lane * 2 + 1];
    float vx = fmaxf(ax * ri + bx, 0.f);
    float vy = fmaxf(ay * ri + by, 0.f);
    if (resid) {
        float2 r = *(const float2*)(resid + (size_t)node * HID + lane * 2);
        vx = fmaxf(vx + r.x, 0.f);
        vy = fmaxf(vy + r.y, 0.f);
    }
    size_t o = (size_t)node * HID + lane * 2;
    if (outX)  { *(float2*)(outX + o) = make_float2(vx, vy); }
    if (outXs) { float ro = rs_out[node]; *(float2*)(outXs + o) = make_float2(vx * ro, vy * ro); }
}

// ---------------- final FC: out[n,41] = X[n,128] @ Wfc + bfc ----------------
__global__ __launch_bounds__(256) void fc_k(const float* __restrict__ X,
                                            const float* __restrict__ Wfc,
                                            const float* __restrict__ bfc,
                                            float* __restrict__ out, int n) {
    __shared__ float Ws[HID * OUTF];
    __shared__ float Xs[4][HID];
    int tid = threadIdx.x;
    for (int i = tid; i < HID * OUTF; i += 256) Ws[i] = Wfc[i];
    int rowBase = blockIdx.x * 4;
    for (int i = tid; i < 4 * HID; i += 256) {
        int r = i >> 7, c = i & 127;
        int gr = rowBase + r;
        Xs[r][c] = (gr < n) ? X[(size_t)gr * HID + c] : 0.f;
    }
    __syncthreads();
    int wv = tid >> 6, lane = tid & 63;
    int row = rowBase + wv;
    if (row < n && lane < OUTF) {
        float acc = bfc[lane];
#pragma unroll 8
        for (int k = 0; k < HID; ++k) acc += Xs[wv][k] * Ws[k * OUTF + lane];
        out[(size_t)row * OUTF + lane] = acc;
    }
}

extern "C" void kernel_launch(void* const* d_in, const int* in_sizes, int n_in,
                              void* d_out, int out_size, void* d_ws, size_t ws_size,
                              hipStream_t stream) {
    const float* feat = (const float*)d_in[0];
    const int* src = (const int*)d_in[1];
    const int* dst = (const int*)d_in[2];
    const float* W1 = (const float*)d_in[3];
    const float* b1 = (const float*)d_in[4];
    const float* W2 = (const float*)d_in[5];
    const float* b2 = (const float*)d_in[6];
    const float* W3 = (const float*)d_in[7];
    const float* b3 = (const float*)d_in[8];
    const float* Wfc = (const float*)d_in[9];
    const float* bfc = (const float*)d_in[10];
    float* out = (float*)d_out;

    char* w = (char*)d_ws;
    auto alloc = [&](size_t b) -> void* {
        void* p = (void*)w;
        w += (b + 255) & ~(size_t)255;
        return p;
    };
    int* cnt_out = (int*)alloc(NN * sizeof(int));
    int* cnt_in  = (int*)alloc(NN * sizeof(int));
    int* rowptr  = (int*)alloc((NN + 1) * sizeof(int));
    int* wcur    = (int*)alloc(NN * sizeof(int));
    int* csrsrc  = (int*)alloc(NE * sizeof(int));
    float* rs_out = (float*)alloc(NN * sizeof(float));
    float* rs_in  = (float*)alloc(NN * sizeof(float));
    float* bufA = (float*)alloc((size_t)NN * HID * sizeof(float));
    float* bufB = (float*)alloc((size_t)NN * HID * sizeof(float));
    float* bufC = (float*)alloc((size_t)NN * HID * sizeof(float));

    hipMemsetAsync(cnt_out, 0, NN * sizeof(int), stream);
    hipMemsetAsync(cnt_in, 0, NN * sizeof(int), stream);

    deg_hist_k<<<(NE + 255) / 256, 256, 0, stream>>>(src, dst, cnt_out, cnt_in, NE);
    scan_k<<<1, 1024, 0, stream>>>(cnt_in, rowptr, wcur, NN);
    fill_csr_k<<<(NE + 255) / 256, 256, 0, stream>>>(src, dst, wcur, csrsrc, NE);
    make_rs_k<<<(NN + 255) / 256, 256, 0, stream>>>(cnt_out, cnt_in, rs_out, rs_in, NN);

    // Layer 1: h1 = (feat * rs_out) @ W1 ; x1s = relu(agg*rs_in + b1) * rs_out
    gemm_k<true><<<(NN + 31) / 32, 256, 0, stream>>>(feat, INF, W1, rs_out, bufA, NN);
    gather_k<<<(NN + 3) / 4, 256, 0, stream>>>(bufA, rowptr, csrsrc, rs_in, rs_out, b1,
                                               nullptr, nullptr, bufB, NN);
    // Layer 2 (x and _x are identical -> compute once): x2 -> bufC (for residual), x2s -> bufB
    gemm_k<false><<<(NN + 31) / 32, 256, 0, stream>>>(bufB, HID, W2, nullptr, bufA, NN);
    gather_k<<<(NN + 3) / 4, 256, 0, stream>>>(bufA, rowptr, csrsrc, rs_in, rs_out, b2,
                                               nullptr, bufC, bufB, NN);
    // Layer 3: x4 = relu(relu(agg*rs_in + b3) + x2) -> bufB
    gemm_k<false><<<(NN + 31) / 32, 256, 0, stream>>>(bufB, HID, W3, nullptr, bufA, NN);
    gather_k<<<(NN + 3) / 4, 256, 0, stream>>>(bufA, rowptr, csrsrc, rs_in, rs_out, b3,
                                               bufC, bufB, nullptr, NN);
    // FC
    fc_k<<<(NN + 3) / 4, 256, 0, stream>>>(bufB, Wfc, bfc, out, NN);
}

// Round 3
// 745.718 us; speedup vs baseline: 1.4269x; 1.4269x over previous
//
#include <hip/hip_runtime.h>
#include <hip/hip_bf16.h>

#define NN   50000
#define NE   600000
#define INF  602
#define HID  128
#define OUTF 41

typedef __attribute__((ext_vector_type(8))) short bf16x8;
typedef __attribute__((ext_vector_type(4))) float f32x4;

__device__ inline unsigned short f2bf(float x) {
    unsigned u = __float_as_uint(x);
    unsigned r = u + 0x7FFF + ((u >> 16) & 1);   // round-to-nearest-even
    return (unsigned short)(r >> 16);
}

// ---------------- degree histogram ----------------
__global__ __launch_bounds__(256) void deg_hist_k(const int* __restrict__ src,
                                                  const int* __restrict__ dst,
                                                  int* __restrict__ cnt_out,
                                                  int* __restrict__ cnt_in, int E) {
    int e = blockIdx.x * 256 + threadIdx.x;
    if (e < E) {
        atomicAdd(&cnt_out[src[e]], 1);
        atomicAdd(&cnt_in[dst[e]], 1);
    }
}

// ---------------- single-block exclusive scan (chunked) ----------------
__global__ __launch_bounds__(1024) void scan_k(const int* __restrict__ cnt,
                                               int* __restrict__ rowptr,
                                               int* __restrict__ wcur, int n) {
    __shared__ int tmp[1024];
    int tid = threadIdx.x;
    int chunk = (n + 1023) >> 10;
    int beg = tid * chunk;
    int end = beg + chunk;
    if (beg > n) beg = n;
    if (end > n) end = n;
    int s = 0;
    for (int i = beg; i < end; ++i) s += cnt[i];
    tmp[tid] = s;
    __syncthreads();
    for (int off = 1; off < 1024; off <<= 1) {
        int t = (tid >= off) ? tmp[tid - off] : 0;
        __syncthreads();
        tmp[tid] += t;
        __syncthreads();
    }
    if (tid == 1023) rowptr[n] = tmp[1023];
    int run = tmp[tid] - s;
    for (int i = beg; i < end; ++i) {
        rowptr[i] = run;
        wcur[i] = run;
        run += cnt[i];
    }
}

// ---------------- CSR fill ----------------
__global__ __launch_bounds__(256) void fill_csr_k(const int* __restrict__ src,
                                                  const int* __restrict__ dst,
                                                  int* __restrict__ wcur,
                                                  int* __restrict__ csrsrc, int E) {
    int e = blockIdx.x * 256 + threadIdx.x;
    if (e < E) {
        int p = atomicAdd(&wcur[dst[e]], 1);
        csrsrc[p] = src[e];
    }
}

// ---------------- rsqrt of clipped degrees ----------------
__global__ __launch_bounds__(256) void make_rs_k(const int* __restrict__ cnt_out,
                                                 const int* __restrict__ cnt_in,
                                                 float* __restrict__ rs_out,
                                                 float* __restrict__ rs_in, int n) {
    int i = blockIdx.x * 256 + threadIdx.x;
    if (i < n) {
        int co = cnt_out[i]; if (co < 1) co = 1;
        int ci = cnt_in[i];  if (ci < 1) ci = 1;
        rs_out[i] = rsqrtf((float)co);
        rs_in[i]  = rsqrtf((float)ci);
    }
}

// ---------------- MFMA GEMM: C[n,128] = (scale? rs[i]*A[i,:] : A[i,:]) @ W[K,128] ----------------
// Block tile 128x128, 4 waves, each wave a 64x64 quadrant (4x4 tiles of 16x16x32 bf16 MFMA).
template <bool SCALE>
__global__ __launch_bounds__(256) void gemm_mfma_k(const float* __restrict__ A, int K,
                                                   const float* __restrict__ W,
                                                   const float* __restrict__ rs,
                                                   float* __restrict__ C, int n) {
    __shared__ short As[128 * 40];       // 128 rows x 32 k, stride 40 (bank-balance pad)
    __shared__ short Bs[4 * 128 * 8];    // [kgroup][col][8k] -> 16B-aligned b128 frag reads

    const int tid = threadIdx.x;
    const int wave = tid >> 6;
    const int lane = tid & 63;
    const int quad = lane >> 4;
    const int l16 = lane & 15;
    const int wm = wave >> 1;            // 0..1  (M half)
    const int wn = wave & 1;             // 0..1  (N half)
    const int rowBase = blockIdx.x * 128;

    f32x4 acc[4][4];
#pragma unroll
    for (int i = 0; i < 4; ++i)
#pragma unroll
        for (int j = 0; j < 4; ++j) acc[i][j] = (f32x4){0.f, 0.f, 0.f, 0.f};

    for (int kb = 0; kb < K; kb += 32) {
        // ---- stage A tile: 128 rows x 32 k (float4 reads, bf16 LDS writes)
#pragma unroll
        for (int ii = 0; ii < 4; ++ii) {
            int i = tid + ii * 256;
            int r = i >> 3;
            int kc = (i & 7) << 2;
            int grow = rowBase + r;
            int gk = kb + kc;
            float v0 = 0.f, v1 = 0.f, v2 = 0.f, v3 = 0.f;
            if (grow < n) {
                if (gk + 3 < K) {
                    float4 t = *(const float4*)(A + (size_t)grow * K + gk);
                    v0 = t.x; v1 = t.y; v2 = t.z; v3 = t.w;
                } else {
                    if (gk + 0 < K) v0 = A[(size_t)grow * K + gk + 0];
                    if (gk + 1 < K) v1 = A[(size_t)grow * K + gk + 1];
                    if (gk + 2 < K) v2 = A[(size_t)grow * K + gk + 2];
                    if (gk + 3 < K) v3 = A[(size_t)grow * K + gk + 3];
                }
                if (SCALE) {
                    float s = rs[grow];
                    v0 *= s; v1 *= s; v2 *= s; v3 *= s;
                }
            }
            short4 h;
            h.x = (short)f2bf(v0); h.y = (short)f2bf(v1);
            h.z = (short)f2bf(v2); h.w = (short)f2bf(v3);
            *(short4*)&As[r * 40 + kc] = h;
        }
        // ---- stage B tile: 32 k x 128 cols, transposed to [g][col][k&7]
#pragma unroll
        for (int ii = 0; ii < 4; ++ii) {
            int i = tid + ii * 256;
            int c = i & 127;
            int k0 = (i >> 7) << 2;      // 0,4,...,28
            int g = k0 >> 3;
            int ko = k0 & 7;             // 0 or 4
            short4 h;
            {
                int gk = kb + k0;
                float v0 = (gk + 0 < K) ? W[(size_t)(gk + 0) * HID + c] : 0.f;
                float v1 = (gk + 1 < K) ? W[(size_t)(gk + 1) * HID + c] : 0.f;
                float v2 = (gk + 2 < K) ? W[(size_t)(gk + 2) * HID + c] : 0.f;
                float v3 = (gk + 3 < K) ? W[(size_t)(gk + 3) * HID + c] : 0.f;
                h.x = (short)f2bf(v0); h.y = (short)f2bf(v1);
                h.z = (short)f2bf(v2); h.w = (short)f2bf(v3);
            }
            *(short4*)&Bs[g * 1024 + c * 8 + ko] = h;
        }
        __syncthreads();

        // ---- fragments + MFMA
        bf16x8 af[4], bfr[4];
#pragma unroll
        for (int mt = 0; mt < 4; ++mt) {
            int row = wm * 64 + mt * 16 + l16;
            af[mt] = *(const bf16x8*)&As[row * 40 + quad * 8];
        }
#pragma unroll
        for (int nt = 0; nt < 4; ++nt) {
            int col = wn * 64 + nt * 16 + l16;
            bfr[nt] = *(const bf16x8*)&Bs[quad * 1024 + col * 8];
        }
#pragma unroll
        for (int mt = 0; mt < 4; ++mt)
#pragma unroll
            for (int nt = 0; nt < 4; ++nt)
                acc[mt][nt] = __builtin_amdgcn_mfma_f32_16x16x32_bf16(af[mt], bfr[nt], acc[mt][nt], 0, 0, 0);
        __syncthreads();
    }

    // ---- epilogue: C/D layout col=lane&15, row=quad*4+reg
#pragma unroll
    for (int mt = 0; mt < 4; ++mt) {
#pragma unroll
        for (int nt = 0; nt < 4; ++nt) {
            int col = wn * 64 + nt * 16 + l16;
#pragma unroll
            for (int r = 0; r < 4; ++r) {
                int row = rowBase + wm * 64 + mt * 16 + quad * 4 + r;
                if (row < n) C[(size_t)row * HID + col] = acc[mt][nt][r];
            }
        }
    }
}

// ---------------- gather + finish: one wave per node, lane = 2 features ----------------
__global__ __launch_bounds__(256) void gather_k(const float* __restrict__ H,
                                                const int* __restrict__ rowptr,
                                                const int* __restrict__ csrsrc,
                                                const float* __restrict__ rs_in,
                                                const float* __restrict__ rs_out,
                                                const float* __restrict__ bias,
                                                const float* __restrict__ resid,  // nullable
                                                float* __restrict__ outX,         // nullable
                                                float* __restrict__ outXs,        // nullable
                                                int n) {
    int node = blockIdx.x * 4 + (threadIdx.x >> 6);
    if (node >= n) return;
    int lane = threadIdx.x & 63;
    int beg = rowptr[node], end = rowptr[node + 1];
    float ax = 0.f, ay = 0.f;
    for (int p = beg; p < end; ++p) {
        int s = csrsrc[p];
        float2 h = *(const float2*)(H + (size_t)s * HID + lane * 2);
        ax += h.x;
        ay += h.y;
    }
    float ri = rs_in[node];
    float bx = bias[lane * 2];
    float by = bias[lane * 2 + 1];
    float vx = fmaxf(ax * ri + bx, 0.f);
    float vy = fmaxf(ay * ri + by, 0.f);
    if (resid) {
        float2 r = *(const float2*)(resid + (size_t)node * HID + lane * 2);
        vx = fmaxf(vx + r.x, 0.f);
        vy = fmaxf(vy + r.y, 0.f);
    }
    size_t o = (size_t)node * HID + lane * 2;
    if (outX)  { *(float2*)(outX + o) = make_float2(vx, vy); }
    if (outXs) { float ro = rs_out[node]; *(float2*)(outXs + o) = make_float2(vx * ro, vy * ro); }
}

// ---------------- final FC: out[n,41] = X[n,128] @ Wfc + bfc ----------------
__global__ __launch_bounds__(256) void fc_k(const float* __restrict__ X,
                                            const float* __restrict__ Wfc,
                                            const float* __restrict__ bfc,
                                            float* __restrict__ out, int n) {
    __shared__ float Ws[HID * OUTF];
    __shared__ float Xs[4][HID];
    int tid = threadIdx.x;
    for (int i = tid; i < HID * OUTF; i += 256) Ws[i] = Wfc[i];
    int rowBase = blockIdx.x * 4;
    for (int i = tid; i < 4 * HID; i += 256) {
        int r = i >> 7, c = i & 127;
        int gr = rowBase + r;
        Xs[r][c] = (gr < n) ? X[(size_t)gr * HID + c] : 0.f;
    }
    __syncthreads();
    int wv = tid >> 6, lane = tid & 63;
    int row = rowBase + wv;
    if (row < n && lane < OUTF) {
        float acc = bfc[lane];
#pragma unroll 8
        for (int k = 0; k < HID; ++k) acc += Xs[wv][k] * Ws[k * OUTF + lane];
        out[(size_t)row * OUTF + lane] = acc;
    }
}

extern "C" void kernel_launch(void* const* d_in, const int* in_sizes, int n_in,
                              void* d_out, int out_size, void* d_ws, size_t ws_size,
                              hipStream_t stream) {
    const float* feat = (const float*)d_in[0];
    const int* src = (const int*)d_in[1];
    const int* dst = (const int*)d_in[2];
    const float* W1 = (const float*)d_in[3];
    const float* b1 = (const float*)d_in[4];
    const float* W2 = (const float*)d_in[5];
    const float* b2 = (const float*)d_in[6];
    const float* W3 = (const float*)d_in[7];
    const float* b3 = (const float*)d_in[8];
    const float* Wfc = (const float*)d_in[9];
    const float* bfc = (const float*)d_in[10];
    float* out = (float*)d_out;

    char* w = (char*)d_ws;
    auto alloc = [&](size_t b) -> void* {
        void* p = (void*)w;
        w += (b + 255) & ~(size_t)255;
        return p;
    };
    int* cnt_out = (int*)alloc(NN * sizeof(int));
    int* cnt_in  = (int*)alloc(NN * sizeof(int));
    int* rowptr  = (int*)alloc((NN + 1) * sizeof(int));
    int* wcur    = (int*)alloc(NN * sizeof(int));
    int* csrsrc  = (int*)alloc(NE * sizeof(int));
    float* rs_out = (float*)alloc(NN * sizeof(float));
    float* rs_in  = (float*)alloc(NN * sizeof(float));
    float* bufA = (float*)alloc((size_t)NN * HID * sizeof(float));
    float* bufB = (float*)alloc((size_t)NN * HID * sizeof(float));
    float* bufC = (float*)alloc((size_t)NN * HID * sizeof(float));

    hipMemsetAsync(cnt_out, 0, NN * sizeof(int), stream);
    hipMemsetAsync(cnt_in, 0, NN * sizeof(int), stream);

    deg_hist_k<<<(NE + 255) / 256, 256, 0, stream>>>(src, dst, cnt_out, cnt_in, NE);
    scan_k<<<1, 1024, 0, stream>>>(cnt_in, rowptr, wcur, NN);
    fill_csr_k<<<(NE + 255) / 256, 256, 0, stream>>>(src, dst, wcur, csrsrc, NE);
    make_rs_k<<<(NN + 255) / 256, 256, 0, stream>>>(cnt_out, cnt_in, rs_out, rs_in, NN);

    const int gblk = (NN + 127) / 128;
    // Layer 1: h1 = (feat * rs_out) @ W1 ; x1s = relu(agg*rs_in + b1) * rs_out
    gemm_mfma_k<true><<<gblk, 256, 0, stream>>>(feat, INF, W1, rs_out, bufA, NN);
    gather_k<<<(NN + 3) / 4, 256, 0, stream>>>(bufA, rowptr, csrsrc, rs_in, rs_out, b1,
                                               nullptr, nullptr, bufB, NN);
    // Layer 2 (x and _x identical -> compute once): x2 -> bufC (residual), x2s -> bufB
    gemm_mfma_k<false><<<gblk, 256, 0, stream>>>(bufB, HID, W2, nullptr, bufA, NN);
    gather_k<<<(NN + 3) / 4, 256, 0, stream>>>(bufA, rowptr, csrsrc, rs_in, rs_out, b2,
                                               nullptr, bufC, bufB, NN);
    // Layer 3: x4 = relu(relu(agg*rs_in + b3) + x2) -> bufB
    gemm_mfma_k<false><<<gblk, 256, 0, stream>>>(bufB, HID, W3, nullptr, bufA, NN);
    gather_k<<<(NN + 3) / 4, 256, 0, stream>>>(bufA, rowptr, csrsrc, rs_in, rs_out, b3,
                                               bufC, bufB, nullptr, NN);
    // FC
    fc_k<<<(NN + 3) / 4, 256, 0, stream>>>(bufB, Wfc, bfc, out, NN);
}

// Round 4
// 716.183 us; speedup vs baseline: 1.4858x; 1.0412x over previous
//
#include <hip/hip_runtime.h>
#include <hip/hip_bf16.h>

#define NN   50000
#define NE   600000
#define INF  602
#define HID  128
#define OUTF 41

typedef __attribute__((ext_vector_type(8))) short bf16x8;
typedef __attribute__((ext_vector_type(4))) float f32x4;

__device__ inline unsigned short f2bf(float x) {
    unsigned u = __float_as_uint(x);
    unsigned r = u + 0x7FFF + ((u >> 16) & 1);   // round-to-nearest-even
    return (unsigned short)(r >> 16);
}

// ---------------- degree histogram ----------------
__global__ __launch_bounds__(256) void deg_hist_k(const int* __restrict__ src,
                                                  const int* __restrict__ dst,
                                                  int* __restrict__ cnt_out,
                                                  int* __restrict__ cnt_in, int E) {
    int e = blockIdx.x * 256 + threadIdx.x;
    if (e < E) {
        atomicAdd(&cnt_out[src[e]], 1);
        atomicAdd(&cnt_in[dst[e]], 1);
    }
}

// ---------------- single-block exclusive scan (chunked) ----------------
__global__ __launch_bounds__(1024) void scan_k(const int* __restrict__ cnt,
                                               int* __restrict__ rowptr,
                                               int* __restrict__ wcur, int n) {
    __shared__ int tmp[1024];
    int tid = threadIdx.x;
    int chunk = (n + 1023) >> 10;
    int beg = tid * chunk;
    int end = beg + chunk;
    if (beg > n) beg = n;
    if (end > n) end = n;
    int s = 0;
    for (int i = beg; i < end; ++i) s += cnt[i];
    tmp[tid] = s;
    __syncthreads();
    for (int off = 1; off < 1024; off <<= 1) {
        int t = (tid >= off) ? tmp[tid - off] : 0;
        __syncthreads();
        tmp[tid] += t;
        __syncthreads();
    }
    if (tid == 1023) rowptr[n] = tmp[1023];
    int run = tmp[tid] - s;
    for (int i = beg; i < end; ++i) {
        rowptr[i] = run;
        wcur[i] = run;
        run += cnt[i];
    }
}

// ---------------- CSR fill ----------------
__global__ __launch_bounds__(256) void fill_csr_k(const int* __restrict__ src,
                                                  const int* __restrict__ dst,
                                                  int* __restrict__ wcur,
                                                  int* __restrict__ csrsrc, int E) {
    int e = blockIdx.x * 256 + threadIdx.x;
    if (e < E) {
        int p = atomicAdd(&wcur[dst[e]], 1);
        csrsrc[p] = src[e];
    }
}

// ---------------- rsqrt of clipped degrees ----------------
__global__ __launch_bounds__(256) void make_rs_k(const int* __restrict__ cnt_out,
                                                 const int* __restrict__ cnt_in,
                                                 float* __restrict__ rs_out,
                                                 float* __restrict__ rs_in, int n) {
    int i = blockIdx.x * 256 + threadIdx.x;
    if (i < n) {
        int co = cnt_out[i]; if (co < 1) co = 1;
        int ci = cnt_in[i];  if (ci < 1) ci = 1;
        rs_out[i] = rsqrtf((float)co);
        rs_in[i]  = rsqrtf((float)ci);
    }
}

// ============ gemm1: C[n,128] = (rs[i]*A[i,:]) @ W[K,128], K=602 ============
// M=64 tiles, BK=64, register-prefetch pipeline. 4 waves: 2x2, each 32x64.
__global__ __launch_bounds__(256) void gemm1_k(const float* __restrict__ A, int K,
                                               const float* __restrict__ W,
                                               const float* __restrict__ rs,
                                               float* __restrict__ C, int n) {
    __shared__ short As[64 * 72];        // [row][k], stride 72 (2-way-free frag reads)
    __shared__ short Bs[8 * 128 * 8];    // [kgroup][col][8k] -> 16B b128 frag reads

    const int tid = threadIdx.x;
    const int wave = tid >> 6;
    const int lane = tid & 63;
    const int quad = lane >> 4;
    const int l16 = lane & 15;
    const int wm = wave >> 1;            // 0..1 (32-row half)
    const int wn = wave & 1;             // 0..1 (64-col half)
    const int rowBase = blockIdx.x * 64;
    const int T = (K + 63) >> 6;

    float4 apf[4];
    float bpf[8][4];
    f32x4 acc[2][4];
#pragma unroll
    for (int i = 0; i < 2; ++i)
#pragma unroll
        for (int j = 0; j < 4; ++j) acc[i][j] = (f32x4){0.f, 0.f, 0.f, 0.f};

    auto loadA = [&](int kb) {
#pragma unroll
        for (int c = 0; c < 4; ++c) {
            int f = c * 256 + tid;
            int row = f >> 4;
            int col4 = (f & 15) << 2;
            int grow = rowBase + row;
            int gk = kb + col4;
            float4 v = {0.f, 0.f, 0.f, 0.f};
            if (grow < n) {
                float s = rs[grow];
                if (gk + 3 < K) {
                    v = *(const float4*)(A + (size_t)grow * K + gk);
                } else {
                    if (gk + 0 < K) v.x = A[(size_t)grow * K + gk + 0];
                    if (gk + 1 < K) v.y = A[(size_t)grow * K + gk + 1];
                    if (gk + 2 < K) v.z = A[(size_t)grow * K + gk + 2];
                }
                v.x *= s; v.y *= s; v.z *= s; v.w *= s;
            }
            apf[c] = v;
        }
    };
    auto loadB = [&](int kb) {
#pragma unroll
        for (int c = 0; c < 8; ++c) {
            int f = c * 256 + tid;
            int col = f & 127;
            int k4 = (f >> 7) << 2;
#pragma unroll
            for (int j = 0; j < 4; ++j) {
                int gk = kb + k4 + j;
                bpf[c][j] = (gk < K) ? W[(size_t)gk * HID + col] : 0.f;
            }
        }
    };
    auto storeAB = [&]() {
#pragma unroll
        for (int c = 0; c < 4; ++c) {
            int f = c * 256 + tid;
            int row = f >> 4;
            int col4 = (f & 15) << 2;
            short4 h;
            h.x = (short)f2bf(apf[c].x); h.y = (short)f2bf(apf[c].y);
            h.z = (short)f2bf(apf[c].z); h.w = (short)f2bf(apf[c].w);
            *(short4*)&As[row * 72 + col4] = h;
        }
#pragma unroll
        for (int c = 0; c < 8; ++c) {
            int f = c * 256 + tid;
            int col = f & 127;
            int k4 = (f >> 7) << 2;
            short4 h;
            h.x = (short)f2bf(bpf[c][0]); h.y = (short)f2bf(bpf[c][1]);
            h.z = (short)f2bf(bpf[c][2]); h.w = (short)f2bf(bpf[c][3]);
            *(short4*)&Bs[(k4 >> 3) * 1024 + col * 8 + (k4 & 7)] = h;
        }
    };

    loadA(0);
    loadB(0);
    for (int t = 0; t < T; ++t) {
        storeAB();
        __syncthreads();
        if (t + 1 < T) {
            loadA((t + 1) << 6);
            loadB((t + 1) << 6);
        }
        // compute on tile t (overlaps the outstanding global loads)
#pragma unroll
        for (int kq = 0; kq < 2; ++kq) {
            bf16x8 af[2], bfr[4];
#pragma unroll
            for (int mt = 0; mt < 2; ++mt)
                af[mt] = *(const bf16x8*)&As[(wm * 32 + mt * 16 + l16) * 72 + kq * 32 + quad * 8];
#pragma unroll
            for (int nt = 0; nt < 4; ++nt)
                bfr[nt] = *(const bf16x8*)&Bs[(kq * 4 + quad) * 1024 + (wn * 64 + nt * 16 + l16) * 8];
#pragma unroll
            for (int mt = 0; mt < 2; ++mt)
#pragma unroll
                for (int nt = 0; nt < 4; ++nt)
                    acc[mt][nt] = __builtin_amdgcn_mfma_f32_16x16x32_bf16(af[mt], bfr[nt], acc[mt][nt], 0, 0, 0);
        }
        __syncthreads();
    }

#pragma unroll
    for (int mt = 0; mt < 2; ++mt)
#pragma unroll
        for (int nt = 0; nt < 4; ++nt) {
            int col = wn * 64 + nt * 16 + l16;
#pragma unroll
            for (int r = 0; r < 4; ++r) {
                int row = rowBase + wm * 32 + mt * 16 + quad * 4 + r;
                if (row < n) C[(size_t)row * HID + col] = acc[mt][nt][r];
            }
        }
}

// ============ gemm_hid: C[n,128] = Abf16[n,128] @ W[128,128], whole-W in LDS ============
__global__ __launch_bounds__(256) void gemm_hid_k(const unsigned short* __restrict__ A,
                                                  const float* __restrict__ W,
                                                  float* __restrict__ C, int n) {
    __shared__ short As[64 * 136];       // [row][k], stride 136
    __shared__ short Bs[16 * 128 * 8];   // [kgroup][col][8k]

    const int tid = threadIdx.x;
    const int wave = tid >> 6;
    const int lane = tid & 63;
    const int quad = lane >> 4;
    const int l16 = lane & 15;
    const int wm = wave >> 1;
    const int wn = wave & 1;
    const int rowBase = blockIdx.x * 64;

    // stage A: 64 rows x 128 k bf16, int4 (8 shorts) per thread x4
#pragma unroll
    for (int c = 0; c < 4; ++c) {
        int f = c * 256 + tid;
        int row = f >> 4;
        int k16 = (f & 15) << 3;
        int grow = rowBase + row;
        int4 v = {0, 0, 0, 0};
        if (grow < n) v = *(const int4*)(A + (size_t)grow * HID + k16);
        *(int4*)&As[row * 136 + k16] = v;
    }
    // stage B: W fp32 -> bf16 transposed [kgroup][col][8]
#pragma unroll
    for (int c = 0; c < 16; ++c) {
        int f = c * 256 + tid;
        int col = f & 127;
        int k4 = (f >> 7) << 2;
        short4 h;
        h.x = (short)f2bf(W[(size_t)(k4 + 0) * HID + col]);
        h.y = (short)f2bf(W[(size_t)(k4 + 1) * HID + col]);
        h.z = (short)f2bf(W[(size_t)(k4 + 2) * HID + col]);
        h.w = (short)f2bf(W[(size_t)(k4 + 3) * HID + col]);
        *(short4*)&Bs[(k4 >> 3) * 1024 + col * 8 + (k4 & 7)] = h;
    }
    __syncthreads();

    f32x4 acc[2][4];
#pragma unroll
    for (int i = 0; i < 2; ++i)
#pragma unroll
        for (int j = 0; j < 4; ++j) acc[i][j] = (f32x4){0.f, 0.f, 0.f, 0.f};

#pragma unroll
    for (int kq = 0; kq < 4; ++kq) {
        bf16x8 af[2], bfr[4];
#pragma unroll
        for (int mt = 0; mt < 2; ++mt)
            af[mt] = *(const bf16x8*)&As[(wm * 32 + mt * 16 + l16) * 136 + kq * 32 + quad * 8];
#pragma unroll
        for (int nt = 0; nt < 4; ++nt)
            bfr[nt] = *(const bf16x8*)&Bs[(kq * 4 + quad) * 1024 + (wn * 64 + nt * 16 + l16) * 8];
#pragma unroll
        for (int mt = 0; mt < 2; ++mt)
#pragma unroll
            for (int nt = 0; nt < 4; ++nt)
                acc[mt][nt] = __builtin_amdgcn_mfma_f32_16x16x32_bf16(af[mt], bfr[nt], acc[mt][nt], 0, 0, 0);
    }

#pragma unroll
    for (int mt = 0; mt < 2; ++mt)
#pragma unroll
        for (int nt = 0; nt < 4; ++nt) {
            int col = wn * 64 + nt * 16 + l16;
#pragma unroll
            for (int r = 0; r < 4; ++r) {
                int row = rowBase + wm * 32 + mt * 16 + quad * 4 + r;
                if (row < n) C[(size_t)row * HID + col] = acc[mt][nt][r];
            }
        }
}

// ---------------- gather + finish: one wave per node, lane = 2 features ----------------
// outXs (bf16) feeds the next GEMM; outX (fp32) is residual / final.
__global__ __launch_bounds__(256) void gather_k(const float* __restrict__ H,
                                                const int* __restrict__ rowptr,
                                                const int* __restrict__ csrsrc,
                                                const float* __restrict__ rs_in,
                                                const float* __restrict__ rs_out,
                                                const float* __restrict__ bias,
                                                const float* __restrict__ resid,     // nullable
                                                float* __restrict__ outX,            // nullable
                                                unsigned short* __restrict__ outXs,  // nullable (bf16)
                                                int n) {
    int node = blockIdx.x * 4 + (threadIdx.x >> 6);
    if (node >= n) return;
    int lane = threadIdx.x & 63;
    int beg = rowptr[node], end = rowptr[node + 1];
    float ax = 0.f, ay = 0.f, bx2 = 0.f, by2 = 0.f;
    int p = beg;
    for (; p + 1 < end; p += 2) {
        int s0 = csrsrc[p];
        int s1 = csrsrc[p + 1];
        float2 h0 = *(const float2*)(H + (size_t)s0 * HID + lane * 2);
        float2 h1 = *(const float2*)(H + (size_t)s1 * HID + lane * 2);
        ax += h0.x; ay += h0.y;
        bx2 += h1.x; by2 += h1.y;
    }
    if (p < end) {
        int s = csrsrc[p];
        float2 h = *(const float2*)(H + (size_t)s * HID + lane * 2);
        ax += h.x; ay += h.y;
    }
    ax += bx2; ay += by2;
    float ri = rs_in[node];
    float vx = fmaxf(ax * ri + bias[lane * 2], 0.f);
    float vy = fmaxf(ay * ri + bias[lane * 2 + 1], 0.f);
    if (resid) {
        float2 r = *(const float2*)(resid + (size_t)node * HID + lane * 2);
        vx = fmaxf(vx + r.x, 0.f);
        vy = fmaxf(vy + r.y, 0.f);
    }
    size_t o = (size_t)node * HID + lane * 2;
    if (outX) { *(float2*)(outX + o) = make_float2(vx, vy); }
    if (outXs) {
        float ro = rs_out[node];
        ushort2 h;
        h.x = f2bf(vx * ro);
        h.y = f2bf(vy * ro);
        *(ushort2*)(outXs + o) = h;
    }
}

// ---------------- final FC: out[n,41] = X[n,128] @ Wfc + bfc ----------------
__global__ __launch_bounds__(256) void fc_k(const float* __restrict__ X,
                                            const float* __restrict__ Wfc,
                                            const float* __restrict__ bfc,
                                            float* __restrict__ out, int n) {
    __shared__ float Ws[HID * OUTF];
    __shared__ float Xs[4][HID];
    int tid = threadIdx.x;
    for (int i = tid; i < HID * OUTF; i += 256) Ws[i] = Wfc[i];
    int rowBase = blockIdx.x * 4;
    for (int i = tid; i < 4 * HID; i += 256) {
        int r = i >> 7, c = i & 127;
        int gr = rowBase + r;
        Xs[r][c] = (gr < n) ? X[(size_t)gr * HID + c] : 0.f;
    }
    __syncthreads();
    int wv = tid >> 6, lane = tid & 63;
    int row = rowBase + wv;
    if (row < n && lane < OUTF) {
        float acc = bfc[lane];
#pragma unroll 8
        for (int k = 0; k < HID; ++k) acc += Xs[wv][k] * Ws[k * OUTF + lane];
        out[(size_t)row * OUTF + lane] = acc;
    }
}

extern "C" void kernel_launch(void* const* d_in, const int* in_sizes, int n_in,
                              void* d_out, int out_size, void* d_ws, size_t ws_size,
                              hipStream_t stream) {
    const float* feat = (const float*)d_in[0];
    const int* src = (const int*)d_in[1];
    const int* dst = (const int*)d_in[2];
    const float* W1 = (const float*)d_in[3];
    const float* b1 = (const float*)d_in[4];
    const float* W2 = (const float*)d_in[5];
    const float* b2 = (const float*)d_in[6];
    const float* W3 = (const float*)d_in[7];
    const float* b3 = (const float*)d_in[8];
    const float* Wfc = (const float*)d_in[9];
    const float* bfc = (const float*)d_in[10];
    float* out = (float*)d_out;

    char* w = (char*)d_ws;
    auto alloc = [&](size_t b) -> void* {
        void* p = (void*)w;
        w += (b + 255) & ~(size_t)255;
        return p;
    };
    int* cnt_out = (int*)alloc(NN * sizeof(int));
    int* cnt_in  = (int*)alloc(NN * sizeof(int));
    int* rowptr  = (int*)alloc((NN + 1) * sizeof(int));
    int* wcur    = (int*)alloc(NN * sizeof(int));
    int* csrsrc  = (int*)alloc(NE * sizeof(int));
    float* rs_out = (float*)alloc(NN * sizeof(float));
    float* rs_in  = (float*)alloc(NN * sizeof(float));
    float* bufA = (float*)alloc((size_t)NN * HID * sizeof(float));
    float* bufB = (float*)alloc((size_t)NN * HID * sizeof(float));
    float* bufC = (float*)alloc((size_t)NN * HID * sizeof(float));

    hipMemsetAsync(cnt_out, 0, NN * sizeof(int), stream);
    hipMemsetAsync(cnt_in, 0, NN * sizeof(int), stream);

    deg_hist_k<<<(NE + 255) / 256, 256, 0, stream>>>(src, dst, cnt_out, cnt_in, NE);
    scan_k<<<1, 1024, 0, stream>>>(cnt_in, rowptr, wcur, NN);
    fill_csr_k<<<(NE + 255) / 256, 256, 0, stream>>>(src, dst, wcur, csrsrc, NE);
    make_rs_k<<<(NN + 255) / 256, 256, 0, stream>>>(cnt_out, cnt_in, rs_out, rs_in, NN);

    const int gblk = (NN + 63) / 64;  // 782
    // Layer 1: h1 = (feat*rs_out) @ W1 ; x1s = bf16(relu(agg*rs_in+b1) * rs_out)
    gemm1_k<<<gblk, 256, 0, stream>>>(feat, INF, W1, rs_out, bufA, NN);
    gather_k<<<(NN + 3) / 4, 256, 0, stream>>>(bufA, rowptr, csrsrc, rs_in, rs_out, b1,
                                               nullptr, nullptr, (unsigned short*)bufB, NN);
    // Layer 2 (x and _x identical -> once): x2 -> bufC (fp32 residual), x2s -> bufB (bf16)
    gemm_hid_k<<<gblk, 256, 0, stream>>>((const unsigned short*)bufB, W2, bufA, NN);
    gather_k<<<(NN + 3) / 4, 256, 0, stream>>>(bufA, rowptr, csrsrc, rs_in, rs_out, b2,
                                               nullptr, bufC, (unsigned short*)bufB, NN);
    // Layer 3: x4 = relu(relu(agg*rs_in+b3) + x2) -> bufB (fp32 for FC)
    gemm_hid_k<<<gblk, 256, 0, stream>>>((const unsigned short*)bufB, W3, bufA, NN);
    gather_k<<<(NN + 3) / 4, 256, 0, stream>>>(bufA, rowptr, csrsrc, rs_in, rs_out, b3,
                                               bufC, bufB, nullptr, NN);
    // FC
    fc_k<<<(NN + 3) / 4, 256, 0, stream>>>(bufB, Wfc, bfc, out, NN);
}

// Round 5
// 614.513 us; speedup vs baseline: 1.7316x; 1.1654x over previous
//
#include <hip/hip_runtime.h>
#include <hip/hip_bf16.h>

#define NN   50000
#define NE   600000
#define INF  602
#define HID  128
#define OUTF 41

typedef __attribute__((ext_vector_type(8))) short bf16x8;
typedef __attribute__((ext_vector_type(4))) float f32x4;

__device__ inline unsigned short f2bf(float x) {
    unsigned u = __float_as_uint(x);
    unsigned r = u + 0x7FFF + ((u >> 16) & 1);   // RNE
    return (unsigned short)(r >> 16);
}

#define GLL16(gp, lp) \
    __builtin_amdgcn_global_load_lds((const __attribute__((address_space(1))) unsigned int*)(gp), \
                                     (__attribute__((address_space(3))) unsigned int*)(lp), 16, 0, 0)

// ---------------- degree histogram ----------------
__global__ __launch_bounds__(256) void deg_hist_k(const int* __restrict__ src,
                                                  const int* __restrict__ dst,
                                                  int* __restrict__ cnt_out,
                                                  int* __restrict__ cnt_in, int E) {
    int e = blockIdx.x * 256 + threadIdx.x;
    if (e < E) {
        atomicAdd(&cnt_out[src[e]], 1);
        atomicAdd(&cnt_in[dst[e]], 1);
    }
}

// ---------------- single-block exclusive scan (chunked) ----------------
__global__ __launch_bounds__(1024) void scan_k(const int* __restrict__ cnt,
                                               int* __restrict__ rowptr,
                                               int* __restrict__ wcur, int n) {
    __shared__ int tmp[1024];
    int tid = threadIdx.x;
    int chunk = (n + 1023) >> 10;
    int beg = tid * chunk;
    int end = beg + chunk;
    if (beg > n) beg = n;
    if (end > n) end = n;
    int s = 0;
    for (int i = beg; i < end; ++i) s += cnt[i];
    tmp[tid] = s;
    __syncthreads();
    for (int off = 1; off < 1024; off <<= 1) {
        int t = (tid >= off) ? tmp[tid - off] : 0;
        __syncthreads();
        tmp[tid] += t;
        __syncthreads();
    }
    if (tid == 1023) rowptr[n] = tmp[1023];
    int run = tmp[tid] - s;
    for (int i = beg; i < end; ++i) {
        rowptr[i] = run;
        wcur[i] = run;
        run += cnt[i];
    }
}

// ---------------- CSR fill ----------------
__global__ __launch_bounds__(256) void fill_csr_k(const int* __restrict__ src,
                                                  const int* __restrict__ dst,
                                                  int* __restrict__ wcur,
                                                  int* __restrict__ csrsrc, int E) {
    int e = blockIdx.x * 256 + threadIdx.x;
    if (e < E) {
        int p = atomicAdd(&wcur[dst[e]], 1);
        csrsrc[p] = src[e];
    }
}

// ---------------- rsqrt of clipped degrees ----------------
__global__ __launch_bounds__(256) void make_rs_k(const int* __restrict__ cnt_out,
                                                 const int* __restrict__ cnt_in,
                                                 float* __restrict__ rs_out,
                                                 float* __restrict__ rs_in, int n) {
    int i = blockIdx.x * 256 + threadIdx.x;
    if (i < n) {
        int co = cnt_out[i]; if (co < 1) co = 1;
        int ci = cnt_in[i];  if (ci < 1) ci = 1;
        rs_out[i] = rsqrtf((float)co);
        rs_in[i]  = rsqrtf((float)ci);
    }
}

// ---------------- weight prep: fp32 [K][128] -> bf16 tiled [k>>3][col][k&7], K padded ----------------
__global__ __launch_bounds__(256) void prep_w_k(const float* __restrict__ W, int K,
                                                unsigned short* __restrict__ out, int total4) {
    int i = blockIdx.x * 256 + threadIdx.x;
    if (i >= total4) return;
    int col = i & 127;
    int k4 = (i >> 7) << 2;
    short4 h;
    h.x = (short)f2bf((k4 + 0 < K) ? W[(size_t)(k4 + 0) * HID + col] : 0.f);
    h.y = (short)f2bf((k4 + 1 < K) ? W[(size_t)(k4 + 1) * HID + col] : 0.f);
    h.z = (short)f2bf((k4 + 2 < K) ? W[(size_t)(k4 + 2) * HID + col] : 0.f);
    h.w = (short)f2bf((k4 + 3 < K) ? W[(size_t)(k4 + 3) * HID + col] : 0.f);
    *(short4*)&out[(size_t)(k4 >> 3) * 1024 + col * 8 + (k4 & 7)] = h;
}

// ============ gemm1: H[n,128] = bf16( rs_out[i] * (A[i,:] @ W1) ), K=602 (pad 640) ============
// M=64 tile, BK=64, B via global_load_lds double-buffer from pre-tiled W1.
__global__ __launch_bounds__(256) void gemm1_k(const float* __restrict__ A,
                                               const unsigned short* __restrict__ Wt,
                                               const float* __restrict__ rs_out,
                                               unsigned short* __restrict__ H, int n) {
    __shared__ __attribute__((aligned(16))) short As[64 * 72];
    __shared__ __attribute__((aligned(16))) short Bs[2][8192];

    const int tid = threadIdx.x;
    const int wave = tid >> 6;
    const int lane = tid & 63;
    const int quad = lane >> 4;
    const int l16 = lane & 15;
    const int wm = wave >> 1;
    const int wn = wave & 1;
    const int rowBase = blockIdx.x * 64;
    const int T = 10;   // 640 / 64

    float4 apf[4];
    auto loadA = [&](int t) {
        int kb = t << 6;
#pragma unroll
        for (int c = 0; c < 4; ++c) {
            int f = c * 256 + tid;
            int row = f >> 4;
            int col4 = (f & 15) << 2;
            int grow = rowBase + row;
            int gk = kb + col4;
            float4 v = {0.f, 0.f, 0.f, 0.f};
            if (grow < n) {
                if (gk + 3 < INF) {
                    v = *(const float4*)(A + (size_t)grow * INF + gk);
                } else {
                    if (gk + 0 < INF) v.x = A[(size_t)grow * INF + gk + 0];
                    if (gk + 1 < INF) v.y = A[(size_t)grow * INF + gk + 1];
                    if (gk + 2 < INF) v.z = A[(size_t)grow * INF + gk + 2];
                }
            }
            apf[c] = v;
        }
    };
    auto storeA = [&]() {
#pragma unroll
        for (int c = 0; c < 4; ++c) {
            int f = c * 256 + tid;
            int row = f >> 4;
            int col4 = (f & 15) << 2;
            short4 h;
            h.x = (short)f2bf(apf[c].x); h.y = (short)f2bf(apf[c].y);
            h.z = (short)f2bf(apf[c].z); h.w = (short)f2bf(apf[c].w);
            *(short4*)&As[row * 72 + col4] = h;
        }
    };
    auto issueB = [&](int t, int p) {
#pragma unroll
        for (int c = 0; c < 4; ++c)
            GLL16(Wt + (size_t)t * 8192 + c * 2048 + tid * 8, &Bs[p][c * 2048 + tid * 8]);
    };

    f32x4 acc[2][4];
#pragma unroll
    for (int i = 0; i < 2; ++i)
#pragma unroll
        for (int j = 0; j < 4; ++j) acc[i][j] = (f32x4){0.f, 0.f, 0.f, 0.f};

    loadA(0);
    issueB(0, 0);
    for (int t = 0; t < T; ++t) {
        storeA();
        __syncthreads();                 // B(t) drained, A(t) visible
        if (t + 1 < T) {
            issueB(t + 1, (t + 1) & 1);  // async into other buffer
            loadA(t + 1);                // regs for next A
        }
        const short* B = Bs[t & 1];
#pragma unroll
        for (int kq = 0; kq < 2; ++kq) {
            bf16x8 af[2], bfr[4];
#pragma unroll
            for (int mt = 0; mt < 2; ++mt)
                af[mt] = *(const bf16x8*)&As[(wm * 32 + mt * 16 + l16) * 72 + kq * 32 + quad * 8];
#pragma unroll
            for (int nt = 0; nt < 4; ++nt)
                bfr[nt] = *(const bf16x8*)&B[(kq * 4 + quad) * 1024 + (wn * 64 + nt * 16 + l16) * 8];
#pragma unroll
            for (int mt = 0; mt < 2; ++mt)
#pragma unroll
                for (int nt = 0; nt < 4; ++nt)
                    acc[mt][nt] = __builtin_amdgcn_mfma_f32_16x16x32_bf16(af[mt], bfr[nt], acc[mt][nt], 0, 0, 0);
        }
        __syncthreads();                 // WAR on As
    }

#pragma unroll
    for (int mt = 0; mt < 2; ++mt)
#pragma unroll
        for (int r = 0; r < 4; ++r) {
            int row = rowBase + wm * 32 + mt * 16 + quad * 4 + r;
            if (row < n) {
                float ro = rs_out[row];
#pragma unroll
                for (int nt = 0; nt < 4; ++nt) {
                    int col = wn * 64 + nt * 16 + l16;
                    H[(size_t)row * HID + col] = f2bf(acc[mt][nt][r] * ro);
                }
            }
        }
}

// ============ gemm_hid: H[n,128] = bf16( Abf16[n,128] @ W[128,128] ), whole-W DMA to LDS ============
__global__ __launch_bounds__(256) void gemm_hid_k(const unsigned short* __restrict__ A,
                                                  const unsigned short* __restrict__ Wt,
                                                  unsigned short* __restrict__ H, int n) {
    __shared__ __attribute__((aligned(16))) short As[64 * 136];
    __shared__ __attribute__((aligned(16))) short Bs[16384];

    const int tid = threadIdx.x;
    const int wave = tid >> 6;
    const int lane = tid & 63;
    const int quad = lane >> 4;
    const int l16 = lane & 15;
    const int wm = wave >> 1;
    const int wn = wave & 1;
    const int rowBase = blockIdx.x * 64;

#pragma unroll
    for (int c = 0; c < 8; ++c)
        GLL16(Wt + c * 2048 + tid * 8, &Bs[c * 2048 + tid * 8]);

#pragma unroll
    for (int c = 0; c < 4; ++c) {
        int f = c * 256 + tid;
        int row = f >> 4;
        int k16 = (f & 15) << 3;
        int grow = rowBase + row;
        int4 v = {0, 0, 0, 0};
        if (grow < n) v = *(const int4*)(A + (size_t)grow * HID + k16);
        *(int4*)&As[row * 136 + k16] = v;
    }
    __syncthreads();

    f32x4 acc[2][4];
#pragma unroll
    for (int i = 0; i < 2; ++i)
#pragma unroll
        for (int j = 0; j < 4; ++j) acc[i][j] = (f32x4){0.f, 0.f, 0.f, 0.f};

#pragma unroll
    for (int kq = 0; kq < 4; ++kq) {
        bf16x8 af[2], bfr[4];
#pragma unroll
        for (int mt = 0; mt < 2; ++mt)
            af[mt] = *(const bf16x8*)&As[(wm * 32 + mt * 16 + l16) * 136 + kq * 32 + quad * 8];
#pragma unroll
        for (int nt = 0; nt < 4; ++nt)
            bfr[nt] = *(const bf16x8*)&Bs[(kq * 4 + quad) * 1024 + (wn * 64 + nt * 16 + l16) * 8];
#pragma unroll
        for (int mt = 0; mt < 2; ++mt)
#pragma unroll
            for (int nt = 0; nt < 4; ++nt)
                acc[mt][nt] = __builtin_amdgcn_mfma_f32_16x16x32_bf16(af[mt], bfr[nt], acc[mt][nt], 0, 0, 0);
    }

#pragma unroll
    for (int mt = 0; mt < 2; ++mt)
#pragma unroll
        for (int r = 0; r < 4; ++r) {
            int row = rowBase + wm * 32 + mt * 16 + quad * 4 + r;
            if (row < n) {
#pragma unroll
                for (int nt = 0; nt < 4; ++nt) {
                    int col = wn * 64 + nt * 16 + l16;
                    H[(size_t)row * HID + col] = f2bf(acc[mt][nt][r]);
                }
            }
        }
}

// ---------------- gather + finish: H is bf16; one wave per node, lane = 2 features ----------------
__global__ __launch_bounds__(256) void gather_k(const unsigned short* __restrict__ H,
                                                const int* __restrict__ rowptr,
                                                const int* __restrict__ csrsrc,
                                                const float* __restrict__ rs_in,
                                                const float* __restrict__ rs_out,
                                                const float* __restrict__ bias,
                                                const float* __restrict__ resid,     // nullable
                                                float* __restrict__ outX,            // nullable
                                                unsigned short* __restrict__ outXs,  // nullable (bf16)
                                                int n) {
    int node = blockIdx.x * 4 + (threadIdx.x >> 6);
    if (node >= n) return;
    int lane = threadIdx.x & 63;
    const unsigned int* Hu = (const unsigned int*)H;   // ushort2 packed
    int beg = rowptr[node], end = rowptr[node + 1];
    float ax = 0.f, ay = 0.f, bx2 = 0.f, by2 = 0.f;
    int p = beg;
    for (; p + 1 < end; p += 2) {
        unsigned u0 = Hu[(size_t)csrsrc[p] * 64 + lane];
        unsigned u1 = Hu[(size_t)csrsrc[p + 1] * 64 + lane];
        ax += __uint_as_float(u0 << 16);
        ay += __uint_as_float(u0 & 0xFFFF0000u);
        bx2 += __uint_as_float(u1 << 16);
        by2 += __uint_as_float(u1 & 0xFFFF0000u);
    }
    if (p < end) {
        unsigned u = Hu[(size_t)csrsrc[p] * 64 + lane];
        ax += __uint_as_float(u << 16);
        ay += __uint_as_float(u & 0xFFFF0000u);
    }
    ax += bx2; ay += by2;
    float ri = rs_in[node];
    float vx = fmaxf(ax * ri + bias[lane * 2], 0.f);
    float vy = fmaxf(ay * ri + bias[lane * 2 + 1], 0.f);
    if (resid) {
        float2 r = *(const float2*)(resid + (size_t)node * HID + lane * 2);
        vx = fmaxf(vx + r.x, 0.f);
        vy = fmaxf(vy + r.y, 0.f);
    }
    size_t o = (size_t)node * HID + lane * 2;
    if (outX) { *(float2*)(outX + o) = make_float2(vx, vy); }
    if (outXs) {
        float ro = rs_out[node];
        ushort2 h;
        h.x = f2bf(vx * ro);
        h.y = f2bf(vy * ro);
        *(ushort2*)(outXs + o) = h;
    }
}

// ---------------- final FC: out[n,41] = X[n,128] @ Wfc + bfc ----------------
__global__ __launch_bounds__(256) void fc_k(const float* __restrict__ X,
                                            const float* __restrict__ Wfc,
                                            const float* __restrict__ bfc,
                                            float* __restrict__ out, int n) {
    __shared__ float Ws[HID * OUTF];
    __shared__ float Xs[4][HID];
    int tid = threadIdx.x;
    for (int i = tid; i < HID * OUTF; i += 256) Ws[i] = Wfc[i];
    int rowBase = blockIdx.x * 4;
    for (int i = tid; i < 4 * HID; i += 256) {
        int r = i >> 7, c = i & 127;
        int gr = rowBase + r;
        Xs[r][c] = (gr < n) ? X[(size_t)gr * HID + c] : 0.f;
    }
    __syncthreads();
    int wv = tid >> 6, lane = tid & 63;
    int row = rowBase + wv;
    if (row < n && lane < OUTF) {
        float acc = bfc[lane];
#pragma unroll 8
        for (int k = 0; k < HID; ++k) acc += Xs[wv][k] * Ws[k * OUTF + lane];
        out[(size_t)row * OUTF + lane] = acc;
    }
}

extern "C" void kernel_launch(void* const* d_in, const int* in_sizes, int n_in,
                              void* d_out, int out_size, void* d_ws, size_t ws_size,
                              hipStream_t stream) {
    const float* feat = (const float*)d_in[0];
    const int* src = (const int*)d_in[1];
    const int* dst = (const int*)d_in[2];
    const float* W1 = (const float*)d_in[3];
    const float* b1 = (const float*)d_in[4];
    const float* W2 = (const float*)d_in[5];
    const float* b2 = (const float*)d_in[6];
    const float* W3 = (const float*)d_in[7];
    const float* b3 = (const float*)d_in[8];
    const float* Wfc = (const float*)d_in[9];
    const float* bfc = (const float*)d_in[10];
    float* out = (float*)d_out;

    char* w = (char*)d_ws;
    auto alloc = [&](size_t b) -> void* {
        void* p = (void*)w;
        w += (b + 255) & ~(size_t)255;
        return p;
    };
    int* cnt_out = (int*)alloc(NN * sizeof(int));
    int* cnt_in  = (int*)alloc(NN * sizeof(int));
    int* rowptr  = (int*)alloc((NN + 1) * sizeof(int));
    int* wcur    = (int*)alloc(NN * sizeof(int));
    int* csrsrc  = (int*)alloc(NE * sizeof(int));
    float* rs_out = (float*)alloc(NN * sizeof(float));
    float* rs_in  = (float*)alloc(NN * sizeof(float));
    unsigned short* W1t = (unsigned short*)alloc(10 * 8192 * sizeof(unsigned short));
    unsigned short* W2t = (unsigned short*)alloc(16384 * sizeof(unsigned short));
    unsigned short* W3t = (unsigned short*)alloc(16384 * sizeof(unsigned short));
    unsigned short* Hb = (unsigned short*)alloc((size_t)NN * HID * sizeof(unsigned short));
    unsigned short* Xb = (unsigned short*)alloc((size_t)NN * HID * sizeof(unsigned short));
    float* resid = (float*)alloc((size_t)NN * HID * sizeof(float));
    float* Xfc   = (float*)alloc((size_t)NN * HID * sizeof(float));

    hipMemsetAsync(cnt_out, 0, NN * sizeof(int), stream);
    hipMemsetAsync(cnt_in, 0, NN * sizeof(int), stream);

    prep_w_k<<<80, 256, 0, stream>>>(W1, INF, W1t, 20480);   // K pad 640
    prep_w_k<<<16, 256, 0, stream>>>(W2, HID, W2t, 4096);
    prep_w_k<<<16, 256, 0, stream>>>(W3, HID, W3t, 4096);

    deg_hist_k<<<(NE + 255) / 256, 256, 0, stream>>>(src, dst, cnt_out, cnt_in, NE);
    scan_k<<<1, 1024, 0, stream>>>(cnt_in, rowptr, wcur, NN);
    fill_csr_k<<<(NE + 255) / 256, 256, 0, stream>>>(src, dst, wcur, csrsrc, NE);
    make_rs_k<<<(NN + 255) / 256, 256, 0, stream>>>(cnt_out, cnt_in, rs_out, rs_in, NN);

    const int gblk = (NN + 63) / 64;  // 782
    // Layer 1: Hb = bf16(rs_out ∘ (feat @ W1)) ; Xb = bf16(relu(agg*ri+b1) * ro)
    gemm1_k<<<gblk, 256, 0, stream>>>(feat, W1t, rs_out, Hb, NN);
    gather_k<<<(NN + 3) / 4, 256, 0, stream>>>(Hb, rowptr, csrsrc, rs_in, rs_out, b1,
                                               nullptr, nullptr, Xb, NN);
    // Layer 2 (computed once, reused for residual): resid = fp32 x2, Xb = bf16(x2 * ro)
    gemm_hid_k<<<gblk, 256, 0, stream>>>(Xb, W2t, Hb, NN);
    gather_k<<<(NN + 3) / 4, 256, 0, stream>>>(Hb, rowptr, csrsrc, rs_in, rs_out, b2,
                                               nullptr, resid, Xb, NN);
    // Layer 3: Xfc = relu(relu(agg*ri+b3) + x2)
    gemm_hid_k<<<gblk, 256, 0, stream>>>(Xb, W3t, Hb, NN);
    gather_k<<<(NN + 3) / 4, 256, 0, stream>>>(Hb, rowptr, csrsrc, rs_in, rs_out, b3,
                                               resid, Xfc, nullptr, NN);
    // FC
    fc_k<<<(NN + 3) / 4, 256, 0, stream>>>(Xfc, Wfc, bfc, out, NN);
}

// Round 6
// 517.041 us; speedup vs baseline: 2.0580x; 1.1885x over previous
//
#include <hip/hip_runtime.h>
#include <hip/hip_bf16.h>

#define NN   50000
#define NE   600000
#define INF  602
#define HID  128
#define OUTF 41
#define NBLK 196   // ceil(NN/256)

typedef __attribute__((ext_vector_type(8))) short bf16x8;
typedef __attribute__((ext_vector_type(4))) float f32x4;

__device__ inline unsigned short f2bf(float x) {
    unsigned u = __float_as_uint(x);
    unsigned r = u + 0x7FFF + ((u >> 16) & 1);   // RNE
    return (unsigned short)(r >> 16);
}

#define GLL16(gp, lp) \
    __builtin_amdgcn_global_load_lds((const __attribute__((address_space(1))) unsigned int*)(gp), \
                                     (__attribute__((address_space(3))) unsigned int*)(lp), 16, 0, 0)

// ---------------- degree histogram ----------------
__global__ __launch_bounds__(256) void deg_hist_k(const int* __restrict__ src,
                                                  const int* __restrict__ dst,
                                                  int* __restrict__ cnt_out,
                                                  int* __restrict__ cnt_in, int E) {
    int e = blockIdx.x * 256 + threadIdx.x;
    if (e < E) {
        atomicAdd(&cnt_out[src[e]], 1);
        atomicAdd(&cnt_in[dst[e]], 1);
    }
}

// ---------------- 3-phase scan ----------------
__global__ __launch_bounds__(256) void scan1_k(const int* __restrict__ cnt,
                                               int* __restrict__ rowptr,
                                               int* __restrict__ blockSum) {
    __shared__ int tmp[256];
    int tid = threadIdx.x;
    int i = blockIdx.x * 256 + tid;
    int v = (i < NN) ? cnt[i] : 0;
    tmp[tid] = v;
    __syncthreads();
#pragma unroll
    for (int off = 1; off < 256; off <<= 1) {
        int t = (tid >= off) ? tmp[tid - off] : 0;
        __syncthreads();
        tmp[tid] += t;
        __syncthreads();
    }
    if (i < NN) rowptr[i] = tmp[tid] - v;      // tile-exclusive
    if (tid == 255) blockSum[blockIdx.x] = tmp[255];
}

__global__ __launch_bounds__(256) void scan2_k(const int* __restrict__ blockSum,
                                               int* __restrict__ blockOff,
                                               int* __restrict__ rowptr) {
    __shared__ int tmp[256];
    int tid = threadIdx.x;
    int v = (tid < NBLK) ? blockSum[tid] : 0;
    tmp[tid] = v;
    __syncthreads();
#pragma unroll
    for (int off = 1; off < 256; off <<= 1) {
        int t = (tid >= off) ? tmp[tid - off] : 0;
        __syncthreads();
        tmp[tid] += t;
        __syncthreads();
    }
    if (tid < NBLK) blockOff[tid] = tmp[tid] - v;
    if (tid == 255) rowptr[NN] = tmp[255];
}

__global__ __launch_bounds__(256) void scan3_k(int* __restrict__ rowptr,
                                               const int* __restrict__ blockOff,
                                               int* __restrict__ wcur,
                                               const int* __restrict__ cnt_out,
                                               const int* __restrict__ cnt_in,
                                               float* __restrict__ rs_out,
                                               float* __restrict__ rs_in) {
    int i = blockIdx.x * 256 + threadIdx.x;
    if (i < NN) {
        int r = rowptr[i] + blockOff[blockIdx.x];
        rowptr[i] = r;
        wcur[i] = r;
        int co = cnt_out[i]; if (co < 1) co = 1;
        int ci = cnt_in[i];  if (ci < 1) ci = 1;
        rs_out[i] = rsqrtf((float)co);
        rs_in[i]  = rsqrtf((float)ci);
    }
}

// ---------------- CSR fill ----------------
__global__ __launch_bounds__(256) void fill_csr_k(const int* __restrict__ src,
                                                  const int* __restrict__ dst,
                                                  int* __restrict__ wcur,
                                                  int* __restrict__ csrsrc, int E) {
    int e = blockIdx.x * 256 + threadIdx.x;
    if (e < E) {
        int p = atomicAdd(&wcur[dst[e]], 1);
        csrsrc[p] = src[e];
    }
}

// ---------------- weight prep: fp32 [K][128] -> bf16 tiled [k>>3][col][k&7], K padded ----------------
__global__ __launch_bounds__(256) void prep_w_k(const float* __restrict__ W, int K,
                                                unsigned short* __restrict__ out, int total4) {
    int i = blockIdx.x * 256 + threadIdx.x;
    if (i >= total4) return;
    int col = i & 127;
    int k4 = (i >> 7) << 2;
    short4 h;
    h.x = (short)f2bf((k4 + 0 < K) ? W[(size_t)(k4 + 0) * HID + col] : 0.f);
    h.y = (short)f2bf((k4 + 1 < K) ? W[(size_t)(k4 + 1) * HID + col] : 0.f);
    h.z = (short)f2bf((k4 + 2 < K) ? W[(size_t)(k4 + 2) * HID + col] : 0.f);
    h.w = (short)f2bf((k4 + 3 < K) ? W[(size_t)(k4 + 3) * HID + col] : 0.f);
    *(short4*)&out[(size_t)(k4 >> 3) * 1024 + col * 8 + (k4 & 7)] = h;
}

// ============ gemm1: H[n,128] = bf16( rs_out[i] * (A[i,:] @ W1) ), K=602 (pad 640) ============
__global__ __launch_bounds__(256) void gemm1_k(const float* __restrict__ A,
                                               const unsigned short* __restrict__ Wt,
                                               const float* __restrict__ rs_out,
                                               unsigned short* __restrict__ H, int n) {
    __shared__ __attribute__((aligned(16))) short As[64 * 72];
    __shared__ __attribute__((aligned(16))) short Bs[2][8192];

    const int tid = threadIdx.x;
    const int wave = tid >> 6;
    const int lane = tid & 63;
    const int quad = lane >> 4;
    const int l16 = lane & 15;
    const int wm = wave >> 1;
    const int wn = wave & 1;
    const int rowBase = blockIdx.x * 64;
    const int T = 10;   // 640 / 64

    float4 apf[4];
    auto loadA = [&](int t) {
        int kb = t << 6;
#pragma unroll
        for (int c = 0; c < 4; ++c) {
            int f = c * 256 + tid;
            int row = f >> 4;
            int col4 = (f & 15) << 2;
            int grow = rowBase + row;
            int gk = kb + col4;
            float4 v = {0.f, 0.f, 0.f, 0.f};
            if (grow < n) {
                if (gk + 3 < INF) {
                    v = *(const float4*)(A + (size_t)grow * INF + gk);
                } else {
                    if (gk + 0 < INF) v.x = A[(size_t)grow * INF + gk + 0];
                    if (gk + 1 < INF) v.y = A[(size_t)grow * INF + gk + 1];
                    if (gk + 2 < INF) v.z = A[(size_t)grow * INF + gk + 2];
                }
            }
            apf[c] = v;
        }
    };
    auto storeA = [&]() {
#pragma unroll
        for (int c = 0; c < 4; ++c) {
            int f = c * 256 + tid;
            int row = f >> 4;
            int col4 = (f & 15) << 2;
            short4 h;
            h.x = (short)f2bf(apf[c].x); h.y = (short)f2bf(apf[c].y);
            h.z = (short)f2bf(apf[c].z); h.w = (short)f2bf(apf[c].w);
            *(short4*)&As[row * 72 + col4] = h;
        }
    };
    auto issueB = [&](int t, int p) {
#pragma unroll
        for (int c = 0; c < 4; ++c)
            GLL16(Wt + (size_t)t * 8192 + c * 2048 + tid * 8, &Bs[p][c * 2048 + tid * 8]);
    };

    f32x4 acc[2][4];
#pragma unroll
    for (int i = 0; i < 2; ++i)
#pragma unroll
        for (int j = 0; j < 4; ++j) acc[i][j] = (f32x4){0.f, 0.f, 0.f, 0.f};

    loadA(0);
    issueB(0, 0);
    for (int t = 0; t < T; ++t) {
        storeA();
        __syncthreads();                 // B(t) drained, A(t) visible
        if (t + 1 < T) {
            issueB(t + 1, (t + 1) & 1);  // async into other buffer
            loadA(t + 1);                // regs for next A
        }
        const short* B = Bs[t & 1];
#pragma unroll
        for (int kq = 0; kq < 2; ++kq) {
            bf16x8 af[2], bfr[4];
#pragma unroll
            for (int mt = 0; mt < 2; ++mt)
                af[mt] = *(const bf16x8*)&As[(wm * 32 + mt * 16 + l16) * 72 + kq * 32 + quad * 8];
#pragma unroll
            for (int nt = 0; nt < 4; ++nt)
                bfr[nt] = *(const bf16x8*)&B[(kq * 4 + quad) * 1024 + (wn * 64 + nt * 16 + l16) * 8];
#pragma unroll
            for (int mt = 0; mt < 2; ++mt)
#pragma unroll
                for (int nt = 0; nt < 4; ++nt)
                    acc[mt][nt] = __builtin_amdgcn_mfma_f32_16x16x32_bf16(af[mt], bfr[nt], acc[mt][nt], 0, 0, 0);
        }
        __syncthreads();                 // WAR on As
    }

#pragma unroll
    for (int mt = 0; mt < 2; ++mt)
#pragma unroll
        for (int r = 0; r < 4; ++r) {
            int row = rowBase + wm * 32 + mt * 16 + quad * 4 + r;
            if (row < n) {
                float ro = rs_out[row];
#pragma unroll
                for (int nt = 0; nt < 4; ++nt) {
                    int col = wn * 64 + nt * 16 + l16;
                    H[(size_t)row * HID + col] = f2bf(acc[mt][nt][r] * ro);
                }
            }
        }
}

// ============ gemm_hid: H[n,128] = bf16( Abf16[n,128] @ W[128,128] ), whole-W DMA to LDS ============
__global__ __launch_bounds__(256) void gemm_hid_k(const unsigned short* __restrict__ A,
                                                  const unsigned short* __restrict__ Wt,
                                                  unsigned short* __restrict__ H, int n) {
    __shared__ __attribute__((aligned(16))) short As[64 * 136];
    __shared__ __attribute__((aligned(16))) short Bs[16384];

    const int tid = threadIdx.x;
    const int wave = tid >> 6;
    const int lane = tid & 63;
    const int quad = lane >> 4;
    const int l16 = lane & 15;
    const int wm = wave >> 1;
    const int wn = wave & 1;
    const int rowBase = blockIdx.x * 64;

#pragma unroll
    for (int c = 0; c < 8; ++c)
        GLL16(Wt + c * 2048 + tid * 8, &Bs[c * 2048 + tid * 8]);

#pragma unroll
    for (int c = 0; c < 4; ++c) {
        int f = c * 256 + tid;
        int row = f >> 4;
        int k16 = (f & 15) << 3;
        int grow = rowBase + row;
        int4 v = {0, 0, 0, 0};
        if (grow < n) v = *(const int4*)(A + (size_t)grow * HID + k16);
        *(int4*)&As[row * 136 + k16] = v;
    }
    __syncthreads();

    f32x4 acc[2][4];
#pragma unroll
    for (int i = 0; i < 2; ++i)
#pragma unroll
        for (int j = 0; j < 4; ++j) acc[i][j] = (f32x4){0.f, 0.f, 0.f, 0.f};

#pragma unroll
    for (int kq = 0; kq < 4; ++kq) {
        bf16x8 af[2], bfr[4];
#pragma unroll
        for (int mt = 0; mt < 2; ++mt)
            af[mt] = *(const bf16x8*)&As[(wm * 32 + mt * 16 + l16) * 136 + kq * 32 + quad * 8];
#pragma unroll
        for (int nt = 0; nt < 4; ++nt)
            bfr[nt] = *(const bf16x8*)&Bs[(kq * 4 + quad) * 1024 + (wn * 64 + nt * 16 + l16) * 8];
#pragma unroll
        for (int mt = 0; mt < 2; ++mt)
#pragma unroll
            for (int nt = 0; nt < 4; ++nt)
                acc[mt][nt] = __builtin_amdgcn_mfma_f32_16x16x32_bf16(af[mt], bfr[nt], acc[mt][nt], 0, 0, 0);
    }

#pragma unroll
    for (int mt = 0; mt < 2; ++mt)
#pragma unroll
        for (int r = 0; r < 4; ++r) {
            int row = rowBase + wm * 32 + mt * 16 + quad * 4 + r;
            if (row < n) {
#pragma unroll
                for (int nt = 0; nt < 4; ++nt) {
                    int col = wn * 64 + nt * 16 + l16;
                    H[(size_t)row * HID + col] = f2bf(acc[mt][nt][r]);
                }
            }
        }
}

// ---------------- gather + finish: H is bf16; one wave per node, lane = 2 features ----------------
__global__ __launch_bounds__(256) void gather_k(const unsigned short* __restrict__ H,
                                                const int* __restrict__ rowptr,
                                                const int* __restrict__ csrsrc,
                                                const float* __restrict__ rs_in,
                                                const float* __restrict__ rs_out,
                                                const float* __restrict__ bias,
                                                const float* __restrict__ resid,     // nullable
                                                float* __restrict__ outX,            // nullable
                                                unsigned short* __restrict__ outXs,  // nullable (bf16)
                                                int n) {
    int node = blockIdx.x * 4 + (threadIdx.x >> 6);
    if (node >= n) return;
    int lane = threadIdx.x & 63;
    const unsigned int* Hu = (const unsigned int*)H;   // ushort2 packed
    int beg = rowptr[node], end = rowptr[node + 1];
    float ax = 0.f, ay = 0.f, bx2 = 0.f, by2 = 0.f;
    int p = beg;
    for (; p + 1 < end; p += 2) {
        unsigned u0 = Hu[(size_t)csrsrc[p] * 64 + lane];
        unsigned u1 = Hu[(size_t)csrsrc[p + 1] * 64 + lane];
        ax += __uint_as_float(u0 << 16);
        ay += __uint_as_float(u0 & 0xFFFF0000u);
        bx2 += __uint_as_float(u1 << 16);
        by2 += __uint_as_float(u1 & 0xFFFF0000u);
    }
    if (p < end) {
        unsigned u = Hu[(size_t)csrsrc[p] * 64 + lane];
        ax += __uint_as_float(u << 16);
        ay += __uint_as_float(u & 0xFFFF0000u);
    }
    ax += bx2; ay += by2;
    float ri = rs_in[node];
    float vx = fmaxf(ax * ri + bias[lane * 2], 0.f);
    float vy = fmaxf(ay * ri + bias[lane * 2 + 1], 0.f);
    if (resid) {
        float2 r = *(const float2*)(resid + (size_t)node * HID + lane * 2);
        vx = fmaxf(vx + r.x, 0.f);
        vy = fmaxf(vy + r.y, 0.f);
    }
    size_t o = (size_t)node * HID + lane * 2;
    if (outX) { *(float2*)(outX + o) = make_float2(vx, vy); }
    if (outXs) {
        float ro = rs_out[node];
        ushort2 h;
        h.x = f2bf(vx * ro);
        h.y = f2bf(vy * ro);
        *(ushort2*)(outXs + o) = h;
    }
}

// ---------------- final FC: out[n,41] = X[n,128] @ Wfc + bfc ----------------
__global__ __launch_bounds__(256) void fc_k(const float* __restrict__ X,
                                            const float* __restrict__ Wfc,
                                            const float* __restrict__ bfc,
                                            float* __restrict__ out, int n) {
    __shared__ float Ws[HID * OUTF];
    __shared__ float Xs[4][HID];
    int tid = threadIdx.x;
    for (int i = tid; i < HID * OUTF; i += 256) Ws[i] = Wfc[i];
    int rowBase = blockIdx.x * 4;
    for (int i = tid; i < 4 * HID; i += 256) {
        int r = i >> 7, c = i & 127;
        int gr = rowBase + r;
        Xs[r][c] = (gr < n) ? X[(size_t)gr * HID + c] : 0.f;
    }
    __syncthreads();
    int wv = tid >> 6, lane = tid & 63;
    int row = rowBase + wv;
    if (row < n && lane < OUTF) {
        float acc = bfc[lane];
#pragma unroll 8
        for (int k = 0; k < HID; ++k) acc += Xs[wv][k] * Ws[k * OUTF + lane];
        out[(size_t)row * OUTF + lane] = acc;
    }
}

extern "C" void kernel_launch(void* const* d_in, const int* in_sizes, int n_in,
                              void* d_out, int out_size, void* d_ws, size_t ws_size,
                              hipStream_t stream) {
    const float* feat = (const float*)d_in[0];
    const int* src = (const int*)d_in[1];
    const int* dst = (const int*)d_in[2];
    const float* W1 = (const float*)d_in[3];
    const float* b1 = (const float*)d_in[4];
    const float* W2 = (const float*)d_in[5];
    const float* b2 = (const float*)d_in[6];
    const float* W3 = (const float*)d_in[7];
    const float* b3 = (const float*)d_in[8];
    const float* Wfc = (const float*)d_in[9];
    const float* bfc = (const float*)d_in[10];
    float* out = (float*)d_out;

    char* w = (char*)d_ws;
    auto alloc = [&](size_t b) -> void* {
        void* p = (void*)w;
        w += (b + 255) & ~(size_t)255;
        return p;
    };
    int* cnt_out = (int*)alloc(NN * sizeof(int));
    int* cnt_in  = (int*)alloc(NN * sizeof(int));
    int* rowptr  = (int*)alloc((NN + 1) * sizeof(int));
    int* wcur    = (int*)alloc(NN * sizeof(int));
    int* csrsrc  = (int*)alloc(NE * sizeof(int));
    int* blockSum = (int*)alloc(NBLK * sizeof(int));
    int* blockOff = (int*)alloc(NBLK * sizeof(int));
    float* rs_out = (float*)alloc(NN * sizeof(float));
    float* rs_in  = (float*)alloc(NN * sizeof(float));
    unsigned short* W1t = (unsigned short*)alloc(10 * 8192 * sizeof(unsigned short));
    unsigned short* W2t = (unsigned short*)alloc(16384 * sizeof(unsigned short));
    unsigned short* W3t = (unsigned short*)alloc(16384 * sizeof(unsigned short));
    unsigned short* Hb = (unsigned short*)alloc((size_t)NN * HID * sizeof(unsigned short));
    unsigned short* Xb = (unsigned short*)alloc((size_t)NN * HID * sizeof(unsigned short));
    float* resid = (float*)alloc((size_t)NN * HID * sizeof(float));
    float* Xfc   = (float*)alloc((size_t)NN * HID * sizeof(float));

    hipMemsetAsync(cnt_out, 0, NN * sizeof(int), stream);
    hipMemsetAsync(cnt_in, 0, NN * sizeof(int), stream);

    prep_w_k<<<80, 256, 0, stream>>>(W1, INF, W1t, 20480);   // K pad 640
    prep_w_k<<<16, 256, 0, stream>>>(W2, HID, W2t, 4096);
    prep_w_k<<<16, 256, 0, stream>>>(W3, HID, W3t, 4096);

    deg_hist_k<<<(NE + 255) / 256, 256, 0, stream>>>(src, dst, cnt_out, cnt_in, NE);
    scan1_k<<<NBLK, 256, 0, stream>>>(cnt_in, rowptr, blockSum);
    scan2_k<<<1, 256, 0, stream>>>(blockSum, blockOff, rowptr);
    scan3_k<<<NBLK, 256, 0, stream>>>(rowptr, blockOff, wcur, cnt_out, cnt_in, rs_out, rs_in);
    fill_csr_k<<<(NE + 255) / 256, 256, 0, stream>>>(src, dst, wcur, csrsrc, NE);

    const int gblk = (NN + 63) / 64;  // 782
    // Layer 1: Hb = bf16(rs_out ∘ (feat @ W1)) ; Xb = bf16(relu(agg*ri+b1) * ro)
    gemm1_k<<<gblk, 256, 0, stream>>>(feat, W1t, rs_out, Hb, NN);
    gather_k<<<(NN + 3) / 4, 256, 0, stream>>>(Hb, rowptr, csrsrc, rs_in, rs_out, b1,
                                               nullptr, nullptr, Xb, NN);
    // Layer 2 (computed once, reused for residual): resid = fp32 x2, Xb = bf16(x2 * ro)
    gemm_hid_k<<<gblk, 256, 0, stream>>>(Xb, W2t, Hb, NN);
    gather_k<<<(NN + 3) / 4, 256, 0, stream>>>(Hb, rowptr, csrsrc, rs_in, rs_out, b2,
                                               nullptr, resid, Xb, NN);
    // Layer 3: Xfc = relu(relu(agg*ri+b3) + x2)
    gemm_hid_k<<<gblk, 256, 0, stream>>>(Xb, W3t, Hb, NN);
    gather_k<<<(NN + 3) / 4, 256, 0, stream>>>(Hb, rowptr, csrsrc, rs_in, rs_out, b3,
                                               resid, Xfc, nullptr, NN);
    // FC
    fc_k<<<(NN + 3) / 4, 256, 0, stream>>>(Xfc, Wfc, bfc, out, NN);
}